// Round 5
// baseline (271.602 us; speedup 1.0000x reference)
//
#include <hip/hip_runtime.h>

#define B_ 32
#define CD 128
#define O3 384
#define N  4096
#define H_ 4
#define C_ 32

typedef __bf16 bf16x8 __attribute__((ext_vector_type(8)));
typedef float floatx4 __attribute__((ext_vector_type(4)));

#define MFMA16(a, b, c) __builtin_amdgcn_mfma_f32_16x16x32_bf16(a, b, c, 0, 0, 0)

__device__ __forceinline__ float b2f(unsigned int u) {   // low 16 bits
  return __builtin_bit_cast(float, u << 16);
}
__device__ __forceinline__ float b2fh(unsigned int u) {  // high 16 bits
  return __builtin_bit_cast(float, u & 0xffff0000u);
}
// RNE fp32 -> bf16 (error-sensitive tensors: xT, vT, Mb, weights)
__device__ __forceinline__ unsigned short f2b(float f) {
  unsigned int bits = __builtin_bit_cast(unsigned int, f);
  unsigned int r = (bits + 0x7FFFu + ((bits >> 16) & 1u)) >> 16;
  return (unsigned short)r;
}
// RTZ fp32 -> bf16 (q,k only: normalize() cancels the toward-zero shrink)
__device__ __forceinline__ unsigned short f2b_rtz(float f) {
  return (unsigned short)(__builtin_bit_cast(unsigned int, f) >> 16);
}

// ---------------------------------------------------------------------------
// K0a: transpose+convert x [b][c][n] fp32 -> xT [b][n][c] bf16 (RNE).
// ---------------------------------------------------------------------------
__global__ __launch_bounds__(256) void k0_xt(const float* __restrict__ x,
                                             unsigned short* __restrict__ xT)
{
  __shared__ float xt[32 * 68];
  const int t = threadIdx.x;
  const int n0 = blockIdx.x * 64, c0 = blockIdx.y * 32, b = blockIdx.z;
  const float* xb = x + ((size_t)b * CD + c0) * N + n0;
#pragma unroll
  for (int i = 0; i < 2; i++) {
    int f = i * 256 + t;
    int c = f >> 4, n4 = (f & 15) * 4;
    float4 v = *(const float4*)(xb + (size_t)c * N + n4);
    *(float4*)&xt[c * 68 + n4] = v;
  }
  __syncthreads();
  int n = t >> 2, cb = (t & 3) * 8;
  unsigned short tmp[8];
#pragma unroll
  for (int j = 0; j < 8; j++) tmp[j] = f2b(xt[(cb + j) * 68 + n]);
  *(uint4*)(xT + ((size_t)b * N + n0 + n) * CD + c0 + cb) = *(uint4*)tmp;
}

// K0b: qkv_w / proj_w fp32 -> bf16 (RNE); pack dw taps (w0,w1,w2,db) float4.
__global__ void k0_w(const float* __restrict__ qkv_w,
                     const float* __restrict__ proj_w,
                     const float* __restrict__ dw_w,
                     const float* __restrict__ dw_b,
                     unsigned short* __restrict__ qkv_wb,
                     unsigned short* __restrict__ proj_wb,
                     float4* __restrict__ dwp)
{
  int tid = blockIdx.x * 256 + threadIdx.x;
  int e = tid * 4;
  const float* src; unsigned short* dst; int off;
  if (e < 49152) { src = qkv_w; dst = qkv_wb; off = e; }
  else           { src = proj_w; dst = proj_wb; off = e - 49152; }
  float4 v = *(const float4*)(src + off);
  unsigned short tmp[4] = {f2b(v.x), f2b(v.y), f2b(v.z), f2b(v.w)};
  *(uint2*)(dst + off) = *(uint2*)tmp;
  if (tid < O3)
    dwp[tid] = make_float4(dw_w[tid * 9 + 1], dw_w[tid * 9 + 4],
                           dw_w[tid * 9 + 7], dw_b[tid]);
}

// ---------------------------------------------------------------------------
// K1: MFMA GEMM (128o x 124y outputs, 128 staged rows incl. 2+2 halo, K=128)
// + bias + 3-tap depthwise + bias.
// q,k: pure-register epilogue — y±1 neighbors via __shfl(width=16) rotates
//      (C-layout col = y = lane&15), RTZ bf16 stores, NO post-MFMA barriers.
// v:   LDS transpose + sliding window -> vT[b][n][c] (RNE).
// grid (34, 3, 32), 256 thr, LDS 34,816 B -> 4 blocks/CU.
// ---------------------------------------------------------------------------
__global__ __launch_bounds__(256, 4) void k1_qkv_dw(
    const unsigned short* __restrict__ xT, const unsigned short* __restrict__ qkv_wb,
    const float* __restrict__ qkv_b, const float4* __restrict__ dwp,
    unsigned short* __restrict__ qkvd, unsigned short* __restrict__ vT)
{
  __shared__ __align__(16) char smem[34816];
  unsigned short* Bs   = (unsigned short*)smem;   // [128][136] staged x rows
  unsigned short* pres = (unsigned short*)smem;   // bf16 pre-dw tile (v alias)

  const int t = threadIdx.x;
  const int ytile = blockIdx.x, otile = blockIdx.y, b = blockIdx.z;
  const int obase = otile * 128;
  const int ybase = ytile * 124;                  // first output y
  const int wv = t >> 6, l = t & 63, quad = l >> 4, lm = l & 15;

  // stage B: rows i=0..127 <-> y = ybase-2+i (zero outside [0,N))
#pragma unroll
  for (int i = 0; i < 8; i++) {
    int f = i * 256 + t;
    int row = f >> 4, c8 = (f & 15) * 8;
    int yg = ybase - 2 + row;
    uint4 v = make_uint4(0u, 0u, 0u, 0u);
    if (yg >= 0 && yg < N)
      v = *(const uint4*)(xT + ((size_t)b * N + yg) * CD + c8);
    *(uint4*)&Bs[row * 136 + c8] = v;
  }
  __syncthreads();

  floatx4 acc[2][8];
#pragma unroll
  for (int mt = 0; mt < 2; mt++)
#pragma unroll
    for (int nt = 0; nt < 8; nt++) acc[mt][nt] = (floatx4){0.f, 0.f, 0.f, 0.f};

  const unsigned short* wbase =
      qkv_wb + (size_t)(obase + wv * 32 + lm) * CD + quad * 8;
#pragma unroll
  for (int ks = 0; ks < 4; ks++) {
    bf16x8 a0 = *(const bf16x8*)(wbase + ks * 32);
    bf16x8 a1 = *(const bf16x8*)(wbase + 16 * CD + ks * 32);
#pragma unroll
    for (int nt = 0; nt < 8; nt++) {
      bf16x8 bb = *(const bf16x8*)&Bs[(nt * 16 + lm) * 136 + ks * 32 + quad * 8];
      acc[0][nt] = MFMA16(a0, bb, acc[0][nt]);
      acc[1][nt] = MFMA16(a1, bb, acc[1][nt]);
    }
  }

  if (otile < 2) {
    // ---- q,k: register-only dw via lane rotates; no barriers, no LDS.
    const int upL = (lm + 15) & 15;   // rotate-up source lane
    const int dnL = (lm + 1) & 15;    // rotate-down source lane
#pragma unroll
    for (int mt = 0; mt < 2; mt++) {
#pragma unroll
      for (int r = 0; r < 4; r++) {
        const int o = wv * 32 + mt * 16 + quad * 4 + r;
        const int oo = obase + o;
        const float4 cw = dwp[oo];
        const float bias = qkv_b[oo];
        float v[8], rU[8], rD[8];
#pragma unroll
        for (int nt = 0; nt < 8; nt++) {
          int yg = ybase - 2 + nt * 16 + lm;
          float pre = acc[mt][nt][r] + bias;
          v[nt] = (yg >= 0 && yg < N) ? pre : 0.f;   // conv zero-padding
        }
#pragma unroll
        for (int nt = 0; nt < 8; nt++) rU[nt] = __shfl(v[nt], upL, 16);
#pragma unroll
        for (int nt = 0; nt < 8; nt++) rD[nt] = __shfl(v[nt], dnL, 16);
        unsigned short* dst =
            qkvd + ((size_t)b * 256 + oo) * N + (ybase - 2 + lm);
#pragma unroll
        for (int nt = 0; nt < 8; nt++) {
          // vm = v(i-1): lane0's rotU wrapped to own tile; take prev tile's.
          float vm = (lm == 0) ? rU[nt > 0 ? nt - 1 : 0] : rU[nt];
          // vp = v(i+1): lane15 wraps; take next tile's rotD.
          float vp = (lm == 15) ? rD[nt < 7 ? nt + 1 : 7] : rD[nt];
          float outv = cw.x * vm + cw.y * v[nt] + cw.z * vp + cw.w;
          int i = nt * 16 + lm;
          int yo = ybase - 2 + i;
          bool ok = (yo < N) && (nt > 0 || lm >= 2) && (nt < 7 || lm <= 13);
          if (ok) dst[nt * 16] = f2b_rtz(outv);
        }
      }
    }
  } else {
    // ---- v: pres[i][o] bf16 RNE; per-lane o, sliding window over y
    const int o = t & 127, half = t >> 7;
    const int oo = obase + o;
    const float4 cw = dwp[oo];
    __syncthreads();   // all waves done reading Bs before alias overwrite
#pragma unroll
    for (int mt = 0; mt < 2; mt++)
#pragma unroll
      for (int r = 0; r < 4; r++) {
        int o2 = wv * 32 + mt * 16 + quad * 4 + r;
        float bias = qkv_b[obase + o2];
#pragma unroll
        for (int nt = 0; nt < 8; nt++) {
          int i = nt * 16 + lm;
          int yg = ybase - 2 + i;
          pres[i * 132 + o2] =
              f2b((yg >= 0 && yg < N) ? (acc[mt][nt][r] + bias) : 0.f);
        }
      }
    __syncthreads();
    int i0 = 2 + half * 62;                     // halves: i 2..63, 64..125
    float pm = b2f((unsigned int)pres[(i0 - 1) * 132 + o]);
    float pc = b2f((unsigned int)pres[i0 * 132 + o]);
    for (int i = i0; i < i0 + 62; i++) {
      float pp = b2f((unsigned int)pres[(i + 1) * 132 + o]);
      int yo = ybase - 2 + i;
      if (yo < N) {
        float v = cw.x * pm + cw.y * pc + cw.z * pp + cw.w;
        vT[((size_t)b * N + yo) * CD + o] = f2b(v);
      }
      pm = pc; pc = pp;
    }
  }
}

// ---------------------------------------------------------------------------
// K3: MFMA Gram, fragments loaded straight from global (K-major layout).
// 32x32 QK^T partial over 1024 n + Q/K norms via self-MFMA diagonals.
// part[b][h][ns][2048]. grid (4, H, B), 256 thr.
// ---------------------------------------------------------------------------
__global__ __launch_bounds__(256, 4) void k3_gram(
    const unsigned short* __restrict__ qkvd, float* __restrict__ part)
{
  __shared__ float red[4 * 8 * 272];   // [wv][tile][row*17+col]
  const int ns = blockIdx.x, h = blockIdx.y, b = blockIdx.z;
  const int t = threadIdx.x;
  const int wv = t >> 6, l = t & 63, quad = l >> 4, lm = l & 15;
  const unsigned short* qb = qkvd + ((size_t)b * 256 + h * C_) * N;
  const unsigned short* kb = qkvd + ((size_t)b * 256 + 128 + h * C_) * N;

  floatx4 acc[8];
#pragma unroll
  for (int i = 0; i < 8; i++) acc[i] = (floatx4){0.f, 0.f, 0.f, 0.f};

  const int nbase = ns * 1024 + wv * 32 + quad * 8;
#pragma unroll
  for (int ch = 0; ch < 8; ch++) {
    int nc = nbase + ch * 128;
    bf16x8 a0 = *(const bf16x8*)(qb + (size_t)lm * N + nc);
    bf16x8 a1 = *(const bf16x8*)(qb + (size_t)(16 + lm) * N + nc);
    bf16x8 b0 = *(const bf16x8*)(kb + (size_t)lm * N + nc);
    bf16x8 b1 = *(const bf16x8*)(kb + (size_t)(16 + lm) * N + nc);
    acc[0] = MFMA16(a0, b0, acc[0]);
    acc[1] = MFMA16(a0, b1, acc[1]);
    acc[2] = MFMA16(a1, b0, acc[2]);
    acc[3] = MFMA16(a1, b1, acc[3]);
    acc[4] = MFMA16(a0, a0, acc[4]);
    acc[5] = MFMA16(a1, a1, acc[5]);
    acc[6] = MFMA16(b0, b0, acc[6]);
    acc[7] = MFMA16(b1, b1, acc[7]);
  }

#pragma unroll
  for (int tl = 0; tl < 8; tl++)
#pragma unroll
    for (int r = 0; r < 4; r++)
      red[wv * 2176 + tl * 272 + (quad * 4 + r) * 17 + lm] = acc[tl][r];
  __syncthreads();

  float* pb = part + ((size_t)(b * H_ + h) * 4 + ns) * 2048;
  for (int e = t; e < 2048; e += 256) {
    int tl = e >> 8, rc = e & 255, row = rc >> 4, col = rc & 15;
    int a = tl * 272 + row * 17 + col;
    float s = red[a] + red[2176 + a] + red[2 * 2176 + a] + red[3 * 2176 + a];
    if (tl < 4) {
      int mt = tl >> 1, nt = tl & 1;
      pb[(mt * 16 + row) * 32 + nt * 16 + col] = s;
    } else if (row == col) {
      if (tl < 6) pb[1024 + (tl - 4) * 16 + row] = s;
      else        pb[1056 + (tl - 6) * 16 + row] = s;
    }
  }
}

// ---------------------------------------------------------------------------
// K45: sum partials, normalize+temperature, exact stable top-k ranks, fold
// 4 masked softmaxes -> AwtT bf16; M = proj_w @ blockdiag(A) via MFMA.
// grid (B), 256 thr.
// ---------------------------------------------------------------------------
__global__ __launch_bounds__(256) void k45(
    const float* __restrict__ part, const unsigned short* __restrict__ proj_wb,
    const float* __restrict__ temperature, const float* __restrict__ attn_w,
    unsigned short* __restrict__ Mb)
{
  __shared__ float La[H_][C_][33];
  __shared__ float sq2[256];
  __shared__ float rn[256];
  __shared__ float exL[H_][C_][33];
  __shared__ unsigned char rkL[H_][C_][C_];
  __shared__ unsigned short AwtT[H_][C_][40];
  const int b = blockIdx.x, t = threadIdx.x;

  const float* pbb = part + (size_t)b * 32768;
  for (int e = t; e < 4 * 2048; e += 256) {
    int h = e >> 11, idx = e & 2047;
    if (idx < 1088) {
      const float* p = pbb + h * 8192 + idx;
      float s = p[0] + p[2048] + p[2 * 2048] + p[3 * 2048];
      if (idx < 1024) La[h][idx >> 5][idx & 31] = s;
      else if (idx < 1056) sq2[h * 32 + (idx - 1024)] = s;
      else sq2[128 + h * 32 + (idx - 1056)] = s;
    }
  }
  __syncthreads();
  rn[t] = 1.f / fmaxf(sqrtf(sq2[t]), 1e-12f);
  __syncthreads();
  for (int e = t; e < 4096; e += 256) {
    int h = e >> 10, i = (e >> 5) & 31, j = e & 31;
    La[h][i][j] *= rn[h * 32 + i] * rn[128 + h * 32 + j] * temperature[h];
  }
  __syncthreads();

  if (t < 128) {
    int h = t >> 5, i = t & 31;
    float m = -1e30f;
    for (int j = 0; j < 32; j++) m = fmaxf(m, La[h][i][j]);
    float S0 = 0.f, S1 = 0.f, S2 = 0.f, S3 = 0.f;
    for (int j = 0; j < 32; j++) {
      float vj = La[h][i][j];
      int r = 0;
      for (int j2 = 0; j2 < 32; j2++) {
        float v2 = La[h][i][j2];
        r += (v2 > vj) || (v2 == vj && j2 < j);
      }
      float e = __expf(vj - m);
      exL[h][i][j] = e;
      rkL[h][i][j] = (unsigned char)r;
      if (r < 16) S0 += e;
      if (r < 21) S1 += e;
      if (r < 24) S2 += e;
      if (r < 25) S3 += e;
    }
    float w0 = attn_w[0] / S0, w1 = attn_w[1] / S1;
    float w2 = attn_w[2] / S2, w3 = attn_w[3] / S3;
    for (int j = 0; j < 32; j++) {
      int r = rkL[h][i][j];
      float cmb = (r < 16 ? w0 : 0.f) + (r < 21 ? w1 : 0.f) +
                  (r < 24 ? w2 : 0.f) + (r < 25 ? w3 : 0.f);
      AwtT[h][j][i] = f2b(exL[h][i][j] * cmb);
    }
  }
  __syncthreads();

  {
    const int wv = t >> 6, l = t & 63, quad = l >> 4, lm = l & 15;
    const int h = wv;
    bf16x8 bfr[2];
#pragma unroll
    for (int jt = 0; jt < 2; jt++)
      bfr[jt] = *(const bf16x8*)&AwtT[h][jt * 16 + lm][quad * 8];
#pragma unroll
    for (int mt = 0; mt < 8; mt++) {
      bf16x8 a = *(const bf16x8*)(proj_wb +
                    (size_t)(mt * 16 + lm) * CD + h * C_ + quad * 8);
#pragma unroll
      for (int jt = 0; jt < 2; jt++) {
        floatx4 acc = (floatx4){0.f, 0.f, 0.f, 0.f};
        acc = MFMA16(a, bfr[jt], acc);
#pragma unroll
        for (int r = 0; r < 4; r++) {
          int row = quad * 4 + r;
          Mb[(size_t)b * 16384 + (mt * 16 + row) * CD + h * C_ + jt * 16 + lm] =
              f2b(acc[r]);
        }
      }
    }
  }
}

// ---------------------------------------------------------------------------
// K6: out[b] = Mb @ V^T + proj_b. A (Mb) per-ks from global (L2-hot);
// LDS = Bs only -> 4 blocks/CU. grid (32, 32), 256 thr.
// ---------------------------------------------------------------------------
__global__ __launch_bounds__(256, 4) void k6_out(
    const unsigned short* __restrict__ vT, const unsigned short* __restrict__ Mb,
    const float* __restrict__ proj_b, float* __restrict__ out)
{
  __shared__ unsigned short Bs[128 * 136];
  const int t = threadIdx.x;
  const int y0 = blockIdx.x * 128, b = blockIdx.y;
  const int wv = t >> 6, l = t & 63, quad = l >> 4, lm = l & 15;

#pragma unroll
  for (int i = 0; i < 8; i++) {
    int f = i * 256 + t;
    int row = f >> 4, c8 = (f & 15) * 8;
    *(uint4*)&Bs[row * 136 + c8] =
        *(const uint4*)(vT + ((size_t)b * N + y0 + row) * CD + c8);
  }
  __syncthreads();

  floatx4 acc[2][8];
#pragma unroll
  for (int mt = 0; mt < 2; mt++)
#pragma unroll
    for (int nt = 0; nt < 8; nt++) acc[mt][nt] = (floatx4){0.f, 0.f, 0.f, 0.f};

  const unsigned short* mbase =
      Mb + (size_t)b * 16384 + (size_t)(wv * 32 + lm) * CD + quad * 8;
#pragma unroll
  for (int ks = 0; ks < 4; ks++) {
    bf16x8 a0 = *(const bf16x8*)(mbase + ks * 32);
    bf16x8 a1 = *(const bf16x8*)(mbase + 16 * CD + ks * 32);
#pragma unroll
    for (int nt = 0; nt < 8; nt++) {
      bf16x8 bb = *(const bf16x8*)&Bs[(nt * 16 + lm) * 136 + ks * 32 + quad * 8];
      acc[0][nt] = MFMA16(a0, bb, acc[0][nt]);
      acc[1][nt] = MFMA16(a1, bb, acc[1][nt]);
    }
  }

#pragma unroll
  for (int mt = 0; mt < 2; mt++)
#pragma unroll
    for (int r = 0; r < 4; r++) {
      int o = wv * 32 + mt * 16 + quad * 4 + r;
      float pb = proj_b[o];
#pragma unroll
      for (int nt = 0; nt < 8; nt++) {
        int y = y0 + nt * 16 + lm;
        out[((size_t)b * CD + o) * N + y] = acc[mt][nt][r] + pb;
      }
    }
}

extern "C" void kernel_launch(void* const* d_in, const int* in_sizes, int n_in,
                              void* d_out, int out_size, void* d_ws, size_t ws_size,
                              hipStream_t stream)
{
  (void)in_sizes; (void)n_in; (void)out_size; (void)ws_size;
  const float* x           = (const float*)d_in[0];
  const float* qkv_w       = (const float*)d_in[1];
  const float* qkv_b       = (const float*)d_in[2];
  const float* dw_w        = (const float*)d_in[3];
  const float* dw_b        = (const float*)d_in[4];
  const float* proj_w      = (const float*)d_in[5];
  const float* proj_b      = (const float*)d_in[6];
  const float* temperature = (const float*)d_in[7];
  const float* attn_w      = (const float*)d_in[8];
  float* out = (float*)d_out;

  unsigned short* xT      = (unsigned short*)d_ws;   // 16,777,216 sh
  unsigned short* qkv_wb  = xT + (size_t)16777216;   //     49,152
  unsigned short* proj_wb = qkv_wb + 49152;          //     16,384
  unsigned short* qkvd    = proj_wb + 16384;         // 33,554,432 (q,k)
  unsigned short* vT      = qkvd + (size_t)33554432; // 16,777,216
  unsigned short* Mb      = vT + (size_t)16777216;   //    524,288
  float* part = (float*)(Mb + 524288);               //  1,048,576 f
  float4* dwp = (float4*)(part + 1048576);           //        384 float4

  k0_xt    <<<dim3(64, 4, 32),  256, 0, stream>>>(x, xT);
  k0_w     <<<dim3(64),         256, 0, stream>>>(qkv_w, proj_w, dw_w, dw_b,
                                                  qkv_wb, proj_wb, dwp);
  k1_qkv_dw<<<dim3(34, 3, 32),  256, 0, stream>>>(xT, qkv_wb, qkv_b, dwp,
                                                  qkvd, vT);
  k3_gram  <<<dim3(4, H_, B_),  256, 0, stream>>>(qkvd, part);
  k45      <<<dim3(B_),         256, 0, stream>>>(part, proj_wb, temperature,
                                                  attn_w, Mb);
  k6_out   <<<dim3(32, B_),     256, 0, stream>>>(vT, Mb, proj_b, out);
}